// Round 2
// baseline (229.307 us; speedup 1.0000x reference)
//
#include <hip/hip_runtime.h>

// Reinsertion: B=32, G=512, D=128, H=4, KD=32. Output (B,G,G) fp32.
//
// R13 = R12 + mlp_pairs latency attack (it measured 44.3us, occupancy 21% --
// latency-bound, all pipes <60%):
//  - g1 tile 16 rows (was 32): grid (2,32,32) = 2048 blocks = 8 blocks/CU,
//    doubles resident waves; per-block prologue is ~1 load/thread so the
//    duplication is free.
//  - epilogue fc3 dot: each 8-deep dependent pk_fma chain split into two
//    4-deep partials (8 independent streams, was 4).
//  - __launch_bounds__(256,4).

#define B 32
#define G 512
#define D 128
#define NH 4
#define KD 32
#define NORMF 0.17677669529663687f  // 1/sqrt(32)

// ws layout:
//  bytes [0, 2048): W2^T f16, wt[col*32 + k]
//  floats [1024, 1056): fc2_b swizzled  bias_sw[half*16 + r] = fc2_b[n(r,half)]
//  floats [1056, 1088): fc3_w swizzled  w3_sw[half*16 + r]   = fc3_w[n(r,half)]
//  half-idx [131072, ...): P fp16 [(b*G+g)*32 + j]
//  half-idx [655360, ...): Q fp16
#define WS_BIASF 1024
#define WS_W3F   1056
#define WS_P16H  131072
#define WS_Q16H  655360

typedef float v16f __attribute__((ext_vector_type(16)));
typedef float f2v __attribute__((ext_vector_type(2)));
typedef _Float16 v8h __attribute__((ext_vector_type(8)));
typedef _Float16 h2v __attribute__((ext_vector_type(2)));

struct HQ { h2v h[4]; };   // 8 halves = 4 VGPRs
struct F2x8 { f2v v[8]; }; // 16 floats as 8 packed pairs

__device__ __forceinline__ v8h relu_add(const HQ& p, const HQ& q) {
  const h2v z = {(_Float16)0.0f, (_Float16)0.0f};
  HQ r;
#pragma unroll
  for (int i = 0; i < 4; ++i)
    r.h[i] = __builtin_elementwise_max(p.h[i] + q.h[i], z);
  return __builtin_bit_cast(v8h, r);
}

// ---------------- Stage 0+1 fused: A-tables (LDS) + P/Q + weight swizzle ----
__global__ __launch_bounds__(256) void stage01(
    const float* __restrict__ h, const int* __restrict__ pp,
    const int* __restrict__ pd, const int* __restrict__ rec,
    const float* __restrict__ Wq1, const float* __restrict__ Wk1,
    const float* __restrict__ Wq2, const float* __restrict__ Wk2,
    const float* __restrict__ fc1_w, const float* __restrict__ fc1_b,
    const float* __restrict__ fc2_w, const float* __restrict__ fc2_b,
    const float* __restrict__ fc3_w,
    float* __restrict__ ws) {
  const int bx = blockIdx.x;
  const int b = bx >> 3, g0 = (bx & 7) * 64;
  const int t = threadIdx.x;

  // Block 0: emit pre-swizzled stage-2 weight tables (tiny, once).
  if (bx == 0 && t < 32) {
    _Float16* wt = (_Float16*)ws;
#pragma unroll
    for (int k = 0; k < 32; ++k) wt[t * 32 + k] = (_Float16)fc2_w[k * 32 + t];
    const int r = t & 15, hf = t >> 4;
    const int n = (r & 3) + 8 * (r >> 2) + 4 * hf;
    ws[WS_BIASF + t] = fc2_b[n];
    ws[WS_W3F + t]   = fc3_w[n];
  }

  __shared__ float hp[D], hd[D];
  __shared__ float qq[4][NH * KD];   // q1p,q2p,q1d,q2d
  __shared__ float sA[4][NH][D];     // Apq,Apo,Adp,Ado
  __shared__ float sc[64][17];
  __shared__ float sout[64][33];
  __shared__ float sout2[64][33];

  if (t < 128) {
    hp[t] = h[((size_t)b * G + pp[b]) * D + t];
  } else {
    const int u = t - 128;
    hd[u] = h[((size_t)b * G + pd[b]) * D + u];
  }
  __syncthreads();

  if (t < 128) {  // t -> (head hh, key k); dot over d
    const int hh = t >> 5, k = t & 31;
    const float* wq1 = Wq1 + hh * D * KD + k;
    const float* wq2 = Wq2 + hh * D * KD + k;
    float s1p = 0.f, s2p = 0.f, s1d = 0.f, s2d = 0.f;
#pragma unroll 8
    for (int d = 0; d < D; ++d) {
      const float w1 = wq1[d * KD], w2 = wq2[d * KD];
      const float xp = hp[d], xd = hd[d];
      s1p = fmaf(xp, w1, s1p);
      s2p = fmaf(xp, w2, s2p);
      s1d = fmaf(xd, w1, s1d);
      s2d = fmaf(xd, w2, s2d);
    }
    qq[0][t] = s1p; qq[1][t] = s2p; qq[2][t] = s1d; qq[3][t] = s2d;
  }
  __syncthreads();

  {  // A[table][hh][d]; thread t: d = t&127, two heads
    const int d = t & 127;
    const int h0 = (t >> 7) * 2;
#pragma unroll
    for (int hh = h0; hh < h0 + 2; ++hh) {
      const float* wk1 = Wk1 + hh * D * KD + d * KD;
      const float* wk2 = Wk2 + hh * D * KD + d * KD;
      float apq = 0.f, apo = 0.f, adp = 0.f, ado = 0.f;
#pragma unroll
      for (int k = 0; k < KD; ++k) {
        const float w1 = wk1[k], w2 = wk2[k];
        apq = fmaf(qq[0][hh * 32 + k], w1, apq);
        adp = fmaf(qq[2][hh * 32 + k], w1, adp);
        apo = fmaf(qq[1][hh * 32 + k], w2, apo);
        ado = fmaf(qq[3][hh * 32 + k], w2, ado);
      }
      sA[0][hh][d] = NORMF * apq;
      sA[1][hh][d] = NORMF * apo;
      sA[2][hh][d] = NORMF * adp;
      sA[3][hh][d] = NORMF * ado;
    }
  }
  __syncthreads();

  // Phase B: compat dots + fc1 decomposition
  const int gl = t & 63;
  const int hh = __builtin_amdgcn_readfirstlane(t >> 6);  // wave id == head
  const int g = g0 + gl;
  const float4* hg4 = (const float4*)(h + ((size_t)b * G + g) * D);
  const float4* hn4 = (const float4*)(h + ((size_t)b * G + rec[b * G + g]) * D);

  float cpp = 0.f, cpo = 0.f, cdp = 0.f, cdo = 0.f;
#pragma unroll 4
  for (int d4 = 0; d4 < 32; ++d4) {
    const float4 x = hg4[d4], y = hn4[d4];
    const float4 a1 = *(const float4*)&sA[0][hh][4 * d4];
    const float4 a2 = *(const float4*)&sA[1][hh][4 * d4];
    const float4 a3 = *(const float4*)&sA[2][hh][4 * d4];
    const float4 a4 = *(const float4*)&sA[3][hh][4 * d4];
    cpp = fmaf(x.x, a1.x, fmaf(x.y, a1.y, fmaf(x.z, a1.z, fmaf(x.w, a1.w, cpp))));
    cpo = fmaf(y.x, a2.x, fmaf(y.y, a2.y, fmaf(y.z, a2.z, fmaf(y.w, a2.w, cpo))));
    cdp = fmaf(x.x, a3.x, fmaf(x.y, a3.y, fmaf(x.z, a3.z, fmaf(x.w, a3.w, cdp))));
    cdo = fmaf(y.x, a4.x, fmaf(y.y, a4.y, fmaf(y.z, a4.z, fmaf(y.w, a4.w, cdo))));
  }
  sc[gl][hh] = cpp; sc[gl][4 + hh] = cpo; sc[gl][8 + hh] = cdp; sc[gl][12 + hh] = cdo;
  __syncthreads();

  float u[16];
#pragma unroll
  for (int i = 0; i < 16; ++i) u[i] = sc[gl][i];

  float pv[8], qv[8];
#pragma unroll
  for (int jj = 0; jj < 8; ++jj) {
    const int j = hh * 8 + jj;  // wave-uniform -> s_load weights
    float p = 0.f, q = fc1_b[j];
#pragma unroll
    for (int i = 0; i < 8; ++i) {
      p = fmaf(u[i], fc1_w[i * 32 + j], p);
      q = fmaf(u[8 + i], fc1_w[(8 + i) * 32 + j], q);
    }
    pv[jj] = p; qv[jj] = q;
  }

  // pack to fp16, transpose via LDS (single fused pass), coalesced uint stores
#pragma unroll
  for (int jj = 0; jj < 8; ++jj) {
    sout[gl][hh * 8 + jj]  = pv[jj];
    sout2[gl][hh * 8 + jj] = qv[jj];
  }
  __syncthreads();
  {
    unsigned* dstP = (unsigned*)((unsigned short*)ws + WS_P16H) +
                     ((size_t)b * G + g0) * 16;
    unsigned* dstQ = (unsigned*)((unsigned short*)ws + WS_Q16H) +
                     ((size_t)b * G + g0) * 16;
#pragma unroll
    for (int i = t; i < 1024; i += 256) {
      const int row = i >> 4, c0 = (2 * i) & 31;
      __fp16 __attribute__((ext_vector_type(2))) pk =
          __builtin_amdgcn_cvt_pkrtz(sout[row][c0], sout[row][c0 + 1]);
      dstP[i] = *(const unsigned*)&pk;
      __fp16 __attribute__((ext_vector_type(2))) qk =
          __builtin_amdgcn_cvt_pkrtz(sout2[row][c0], sout2[row][c0 + 1]);
      dstQ[i] = *(const unsigned*)&qk;
    }
  }
}

// ---------------- Stage 2: per-pair MLP via 32x32x16 f16 MFMA ----------------
// Grid (2,32,32); block 256 = 4 waves; block tile 16 g1 x 256 g2; wave w owns
// chunks {2w,2w+1} of 32 g2. 8 iterations x (2 g1 rows x 2 chunks) = 4
// independent MFMA chains per iteration; epilogue fc3 dot uses 2 partial
// accumulators per chain (8 independent FMA streams). All prologue operands
// come from pre-swizzled ws tables via wide vector loads.
__global__ __launch_bounds__(256, 4) void mlp_pairs(
    const float* __restrict__ ws, const float* __restrict__ fc3_b,
    float* __restrict__ out) {
  const int b = blockIdx.z;
  const int g1_0 = blockIdx.y * 16;
  const int g2_0 = blockIdx.x * 256;
  const int t = threadIdx.x;
  const int w = t >> 6, l = t & 63;
  const int col = l & 31;   // pair within chunk
  const int half = l >> 5;  // k-subrange / n-subset selector
  const int kb = half * 8;

  __shared__ __align__(16) unsigned short sPh[16 * 32];  // 1 KB P tile
  {
    const unsigned* Psrc = (const unsigned*)((const unsigned short*)ws + WS_P16H) +
                           ((size_t)b * G + g1_0) * 16;
    ((unsigned*)sPh)[t] = Psrc[t];
  }

  // A-frags from pre-swizzled W2^T f16 [col][k]: 2 x 16B loads
  const unsigned short* wt = (const unsigned short*)ws;
  const v8h A0 = __builtin_bit_cast(v8h, *(const uint4*)(wt + col * 32 + kb));
  const v8h A1 = __builtin_bit_cast(v8h, *(const uint4*)(wt + col * 32 + 16 + kb));
  // Bias / fc3 weights pre-swizzled in n-map order: 64B vector loads
  const v16f biasC = *(const v16f*)(ws + WS_BIASF + half * 16);
  const F2x8 w3p = __builtin_bit_cast(F2x8, *(const v16f*)(ws + WS_W3F + half * 16));
  // fc3_b folded into the epilogue accumulator: each half contributes b3/2,
  // the cross-half shuffle-add reassembles the full b3.
  const float b3h = 0.5f * fc3_b[0];

  // Q fragments (g1-invariant, fp16) for both chunks
  HQ qlo[2], qhi[2];
#pragma unroll
  for (int c = 0; c < 2; ++c) {
    const unsigned short* qp = (const unsigned short*)ws + WS_Q16H +
        ((size_t)b * G + g2_0 + (2 * w + c) * 32 + col) * 32;
    qlo[c] = __builtin_bit_cast(HQ, *(const uint4*)(qp + kb));
    qhi[c] = __builtin_bit_cast(HQ, *(const uint4*)(qp + 16 + kb));
  }
  __syncthreads();

  const f2v binit = {b3h, 0.f};
  const f2v z2 = {0.f, 0.f};
  float* op = out + (((size_t)b * G + g1_0) * G) + g2_0 + w * 64 + half * 32 + col;
#pragma unroll 4
  for (int i = 0; i < 8; ++i) {
    const int ra = 2 * i, rb = 2 * i + 1;
    const HQ palo = __builtin_bit_cast(HQ, *(const uint4*)(sPh + ra * 32 + kb));
    const HQ pahi = __builtin_bit_cast(HQ, *(const uint4*)(sPh + ra * 32 + 16 + kb));
    const HQ pblo = __builtin_bit_cast(HQ, *(const uint4*)(sPh + rb * 32 + kb));
    const HQ pbhi = __builtin_bit_cast(HQ, *(const uint4*)(sPh + rb * 32 + 16 + kb));

    // 8 B-frags, 8 MFMAs: 4 independent chains
    const v8h Ba0lo = relu_add(palo, qlo[0]);
    const v8h Ba0hi = relu_add(pahi, qhi[0]);
    const v8h Ba1lo = relu_add(palo, qlo[1]);
    const v8h Ba1hi = relu_add(pahi, qhi[1]);
    const v8h Bb0lo = relu_add(pblo, qlo[0]);
    const v8h Bb0hi = relu_add(pbhi, qhi[0]);
    const v8h Bb1lo = relu_add(pblo, qlo[1]);
    const v8h Bb1hi = relu_add(pbhi, qhi[1]);

    v16f aa0 = __builtin_amdgcn_mfma_f32_32x32x16_f16(A0, Ba0lo, biasC, 0, 0, 0);
    v16f aa1 = __builtin_amdgcn_mfma_f32_32x32x16_f16(A0, Ba1lo, biasC, 0, 0, 0);
    v16f ab0 = __builtin_amdgcn_mfma_f32_32x32x16_f16(A0, Bb0lo, biasC, 0, 0, 0);
    v16f ab1 = __builtin_amdgcn_mfma_f32_32x32x16_f16(A0, Bb1lo, biasC, 0, 0, 0);
    aa0 = __builtin_amdgcn_mfma_f32_32x32x16_f16(A1, Ba0hi, aa0, 0, 0, 0);
    aa1 = __builtin_amdgcn_mfma_f32_32x32x16_f16(A1, Ba1hi, aa1, 0, 0, 0);
    ab0 = __builtin_amdgcn_mfma_f32_32x32x16_f16(A1, Bb0hi, ab0, 0, 0, 0);
    ab1 = __builtin_amdgcn_mfma_f32_32x32x16_f16(A1, Bb1hi, ab1, 0, 0, 0);

    // 4 packed-fp32 epilogues, each with 2 partial accumulators (4-deep
    // dependency chains instead of 8-deep)
    const F2x8 fa0 = __builtin_bit_cast(F2x8, aa0);
    const F2x8 fa1 = __builtin_bit_cast(F2x8, aa1);
    const F2x8 fb0 = __builtin_bit_cast(F2x8, ab0);
    const F2x8 fb1 = __builtin_bit_cast(F2x8, ab1);
    f2v ea0a = binit, ea1a = binit, eb0a = binit, eb1a = binit;
    f2v ea0b = z2, ea1b = z2, eb0b = z2, eb1b = z2;
#pragma unroll
    for (int k = 0; k < 4; ++k) {
      ea0a = __builtin_elementwise_max(fa0.v[k], z2) * w3p.v[k] + ea0a;
      ea1a = __builtin_elementwise_max(fa1.v[k], z2) * w3p.v[k] + ea1a;
      eb0a = __builtin_elementwise_max(fb0.v[k], z2) * w3p.v[k] + eb0a;
      eb1a = __builtin_elementwise_max(fb1.v[k], z2) * w3p.v[k] + eb1a;
      ea0b = __builtin_elementwise_max(fa0.v[k + 4], z2) * w3p.v[k + 4] + ea0b;
      ea1b = __builtin_elementwise_max(fa1.v[k + 4], z2) * w3p.v[k + 4] + ea1b;
      eb0b = __builtin_elementwise_max(fb0.v[k + 4], z2) * w3p.v[k + 4] + eb0b;
      eb1b = __builtin_elementwise_max(fb1.v[k + 4], z2) * w3p.v[k + 4] + eb1b;
    }
    const f2v ea0 = ea0a + ea0b, ea1 = ea1a + ea1b;
    const f2v eb0 = eb0a + eb0b, eb1 = eb1a + eb1b;
    const float sa0 = ea0[0] + ea0[1], sa1 = ea1[0] + ea1[1];
    const float sb0 = eb0[0] + eb0[1], sb1 = eb1[0] + eb1[1];

    // single-shuffle cross-half reduce per row (select-swap)
    float ya = half ? sa1 : sa0;
    float za = half ? sa0 : sa1;
    ya += __shfl_xor(za, 32);
    float yb = half ? sb1 : sb0;
    float zb = half ? sb0 : sb1;
    yb += __shfl_xor(zb, 32);

    op[(size_t)ra * G] = ya;
    op[(size_t)rb * G] = yb;
  }
}

extern "C" void kernel_launch(void* const* d_in, const int* in_sizes, int n_in,
                              void* d_out, int out_size, void* d_ws, size_t ws_size,
                              hipStream_t stream) {
  const float* h     = (const float*)d_in[0];
  const int*   pp    = (const int*)d_in[1];
  const int*   pd    = (const int*)d_in[2];
  const int*   rec   = (const int*)d_in[3];
  const float* Wq1   = (const float*)d_in[4];
  const float* Wk1   = (const float*)d_in[5];
  const float* Wq2   = (const float*)d_in[6];
  const float* Wk2   = (const float*)d_in[7];
  const float* fc1_w = (const float*)d_in[8];
  const float* fc1_b = (const float*)d_in[9];
  const float* fc2_w = (const float*)d_in[10];
  const float* fc2_b = (const float*)d_in[11];
  const float* fc3_w = (const float*)d_in[12];
  const float* fc3_b = (const float*)d_in[13];
  float* out = (float*)d_out;
  float* ws  = (float*)d_ws;

  stage01<<<dim3(256), dim3(256), 0, stream>>>(
      h, pp, pd, rec, Wq1, Wk1, Wq2, Wk2, fc1_w, fc1_b, fc2_w, fc2_b, fc3_w, ws);
  mlp_pairs<<<dim3(2, 32, 32), dim3(256), 0, stream>>>(ws, fc3_b, out);
}

// Round 3
// 147.006 us; speedup vs baseline: 1.5598x; 1.5598x over previous
//
#include <hip/hip_runtime.h>

// Reinsertion: B=32, G=512, D=128, H=4, KD=32. Output (B,G,G) fp32.
//
// R14 = R13 with the register squeeze reverted. R13's __launch_bounds__(256,4)
// forced VGPR 76->64 and spilled the MFMA fragments to scratch: FETCH_SIZE
// 3MB->260MB, WRITE_SIZE 33.5MB->178MB per dispatch, dur 44->130us. Keep the
// 16-row g1 tile (2048 blocks) + split epilogue; restore (256,2).

#define B 32
#define G 512
#define D 128
#define NH 4
#define KD 32
#define NORMF 0.17677669529663687f  // 1/sqrt(32)

// ws layout:
//  bytes [0, 2048): W2^T f16, wt[col*32 + k]
//  floats [1024, 1056): fc2_b swizzled  bias_sw[half*16 + r] = fc2_b[n(r,half)]
//  floats [1056, 1088): fc3_w swizzled  w3_sw[half*16 + r]   = fc3_w[n(r,half)]
//  half-idx [131072, ...): P fp16 [(b*G+g)*32 + j]
//  half-idx [655360, ...): Q fp16
#define WS_BIASF 1024
#define WS_W3F   1056
#define WS_P16H  131072
#define WS_Q16H  655360

typedef float v16f __attribute__((ext_vector_type(16)));
typedef float f2v __attribute__((ext_vector_type(2)));
typedef _Float16 v8h __attribute__((ext_vector_type(8)));
typedef _Float16 h2v __attribute__((ext_vector_type(2)));

struct HQ { h2v h[4]; };   // 8 halves = 4 VGPRs
struct F2x8 { f2v v[8]; }; // 16 floats as 8 packed pairs

__device__ __forceinline__ v8h relu_add(const HQ& p, const HQ& q) {
  const h2v z = {(_Float16)0.0f, (_Float16)0.0f};
  HQ r;
#pragma unroll
  for (int i = 0; i < 4; ++i)
    r.h[i] = __builtin_elementwise_max(p.h[i] + q.h[i], z);
  return __builtin_bit_cast(v8h, r);
}

// ---------------- Stage 0+1 fused: A-tables (LDS) + P/Q + weight swizzle ----
__global__ __launch_bounds__(256) void stage01(
    const float* __restrict__ h, const int* __restrict__ pp,
    const int* __restrict__ pd, const int* __restrict__ rec,
    const float* __restrict__ Wq1, const float* __restrict__ Wk1,
    const float* __restrict__ Wq2, const float* __restrict__ Wk2,
    const float* __restrict__ fc1_w, const float* __restrict__ fc1_b,
    const float* __restrict__ fc2_w, const float* __restrict__ fc2_b,
    const float* __restrict__ fc3_w,
    float* __restrict__ ws) {
  const int bx = blockIdx.x;
  const int b = bx >> 3, g0 = (bx & 7) * 64;
  const int t = threadIdx.x;

  // Block 0: emit pre-swizzled stage-2 weight tables (tiny, once).
  if (bx == 0 && t < 32) {
    _Float16* wt = (_Float16*)ws;
#pragma unroll
    for (int k = 0; k < 32; ++k) wt[t * 32 + k] = (_Float16)fc2_w[k * 32 + t];
    const int r = t & 15, hf = t >> 4;
    const int n = (r & 3) + 8 * (r >> 2) + 4 * hf;
    ws[WS_BIASF + t] = fc2_b[n];
    ws[WS_W3F + t]   = fc3_w[n];
  }

  __shared__ float hp[D], hd[D];
  __shared__ float qq[4][NH * KD];   // q1p,q2p,q1d,q2d
  __shared__ float sA[4][NH][D];     // Apq,Apo,Adp,Ado
  __shared__ float sc[64][17];
  __shared__ float sout[64][33];
  __shared__ float sout2[64][33];

  if (t < 128) {
    hp[t] = h[((size_t)b * G + pp[b]) * D + t];
  } else {
    const int u = t - 128;
    hd[u] = h[((size_t)b * G + pd[b]) * D + u];
  }
  __syncthreads();

  if (t < 128) {  // t -> (head hh, key k); dot over d
    const int hh = t >> 5, k = t & 31;
    const float* wq1 = Wq1 + hh * D * KD + k;
    const float* wq2 = Wq2 + hh * D * KD + k;
    float s1p = 0.f, s2p = 0.f, s1d = 0.f, s2d = 0.f;
#pragma unroll 8
    for (int d = 0; d < D; ++d) {
      const float w1 = wq1[d * KD], w2 = wq2[d * KD];
      const float xp = hp[d], xd = hd[d];
      s1p = fmaf(xp, w1, s1p);
      s2p = fmaf(xp, w2, s2p);
      s1d = fmaf(xd, w1, s1d);
      s2d = fmaf(xd, w2, s2d);
    }
    qq[0][t] = s1p; qq[1][t] = s2p; qq[2][t] = s1d; qq[3][t] = s2d;
  }
  __syncthreads();

  {  // A[table][hh][d]; thread t: d = t&127, two heads
    const int d = t & 127;
    const int h0 = (t >> 7) * 2;
#pragma unroll
    for (int hh = h0; hh < h0 + 2; ++hh) {
      const float* wk1 = Wk1 + hh * D * KD + d * KD;
      const float* wk2 = Wk2 + hh * D * KD + d * KD;
      float apq = 0.f, apo = 0.f, adp = 0.f, ado = 0.f;
#pragma unroll
      for (int k = 0; k < KD; ++k) {
        const float w1 = wk1[k], w2 = wk2[k];
        apq = fmaf(qq[0][hh * 32 + k], w1, apq);
        adp = fmaf(qq[2][hh * 32 + k], w1, adp);
        apo = fmaf(qq[1][hh * 32 + k], w2, apo);
        ado = fmaf(qq[3][hh * 32 + k], w2, ado);
      }
      sA[0][hh][d] = NORMF * apq;
      sA[1][hh][d] = NORMF * apo;
      sA[2][hh][d] = NORMF * adp;
      sA[3][hh][d] = NORMF * ado;
    }
  }
  __syncthreads();

  // Phase B: compat dots + fc1 decomposition
  const int gl = t & 63;
  const int hh = __builtin_amdgcn_readfirstlane(t >> 6);  // wave id == head
  const int g = g0 + gl;
  const float4* hg4 = (const float4*)(h + ((size_t)b * G + g) * D);
  const float4* hn4 = (const float4*)(h + ((size_t)b * G + rec[b * G + g]) * D);

  float cpp = 0.f, cpo = 0.f, cdp = 0.f, cdo = 0.f;
#pragma unroll 4
  for (int d4 = 0; d4 < 32; ++d4) {
    const float4 x = hg4[d4], y = hn4[d4];
    const float4 a1 = *(const float4*)&sA[0][hh][4 * d4];
    const float4 a2 = *(const float4*)&sA[1][hh][4 * d4];
    const float4 a3 = *(const float4*)&sA[2][hh][4 * d4];
    const float4 a4 = *(const float4*)&sA[3][hh][4 * d4];
    cpp = fmaf(x.x, a1.x, fmaf(x.y, a1.y, fmaf(x.z, a1.z, fmaf(x.w, a1.w, cpp))));
    cpo = fmaf(y.x, a2.x, fmaf(y.y, a2.y, fmaf(y.z, a2.z, fmaf(y.w, a2.w, cpo))));
    cdp = fmaf(x.x, a3.x, fmaf(x.y, a3.y, fmaf(x.z, a3.z, fmaf(x.w, a3.w, cdp))));
    cdo = fmaf(y.x, a4.x, fmaf(y.y, a4.y, fmaf(y.z, a4.z, fmaf(y.w, a4.w, cdo))));
  }
  sc[gl][hh] = cpp; sc[gl][4 + hh] = cpo; sc[gl][8 + hh] = cdp; sc[gl][12 + hh] = cdo;
  __syncthreads();

  float u[16];
#pragma unroll
  for (int i = 0; i < 16; ++i) u[i] = sc[gl][i];

  float pv[8], qv[8];
#pragma unroll
  for (int jj = 0; jj < 8; ++jj) {
    const int j = hh * 8 + jj;  // wave-uniform -> s_load weights
    float p = 0.f, q = fc1_b[j];
#pragma unroll
    for (int i = 0; i < 8; ++i) {
      p = fmaf(u[i], fc1_w[i * 32 + j], p);
      q = fmaf(u[8 + i], fc1_w[(8 + i) * 32 + j], q);
    }
    pv[jj] = p; qv[jj] = q;
  }

  // pack to fp16, transpose via LDS (single fused pass), coalesced uint stores
#pragma unroll
  for (int jj = 0; jj < 8; ++jj) {
    sout[gl][hh * 8 + jj]  = pv[jj];
    sout2[gl][hh * 8 + jj] = qv[jj];
  }
  __syncthreads();
  {
    unsigned* dstP = (unsigned*)((unsigned short*)ws + WS_P16H) +
                     ((size_t)b * G + g0) * 16;
    unsigned* dstQ = (unsigned*)((unsigned short*)ws + WS_Q16H) +
                     ((size_t)b * G + g0) * 16;
#pragma unroll
    for (int i = t; i < 1024; i += 256) {
      const int row = i >> 4, c0 = (2 * i) & 31;
      __fp16 __attribute__((ext_vector_type(2))) pk =
          __builtin_amdgcn_cvt_pkrtz(sout[row][c0], sout[row][c0 + 1]);
      dstP[i] = *(const unsigned*)&pk;
      __fp16 __attribute__((ext_vector_type(2))) qk =
          __builtin_amdgcn_cvt_pkrtz(sout2[row][c0], sout2[row][c0 + 1]);
      dstQ[i] = *(const unsigned*)&qk;
    }
  }
}

// ---------------- Stage 2: per-pair MLP via 32x32x16 f16 MFMA ----------------
// Grid (2,32,32); block 256 = 4 waves; block tile 16 g1 x 256 g2; wave w owns
// chunks {2w,2w+1} of 32 g2. 8 iterations x (2 g1 rows x 2 chunks) = 4
// independent MFMA chains per iteration; epilogue fc3 dot uses 2 partial
// accumulators per chain (8 independent FMA streams). All prologue operands
// come from pre-swizzled ws tables via wide vector loads.
// NOTE: launch bounds (256,2) -- NOT (256,4): the 4-wave hint drops VGPR to 64
// and spills fragments to scratch (R13: +400MB HBM traffic, 3x slower).
__global__ __launch_bounds__(256, 2) void mlp_pairs(
    const float* __restrict__ ws, const float* __restrict__ fc3_b,
    float* __restrict__ out) {
  const int b = blockIdx.z;
  const int g1_0 = blockIdx.y * 16;
  const int g2_0 = blockIdx.x * 256;
  const int t = threadIdx.x;
  const int w = t >> 6, l = t & 63;
  const int col = l & 31;   // pair within chunk
  const int half = l >> 5;  // k-subrange / n-subset selector
  const int kb = half * 8;

  __shared__ __align__(16) unsigned short sPh[16 * 32];  // 1 KB P tile
  {
    const unsigned* Psrc = (const unsigned*)((const unsigned short*)ws + WS_P16H) +
                           ((size_t)b * G + g1_0) * 16;
    ((unsigned*)sPh)[t] = Psrc[t];
  }

  // A-frags from pre-swizzled W2^T f16 [col][k]: 2 x 16B loads
  const unsigned short* wt = (const unsigned short*)ws;
  const v8h A0 = __builtin_bit_cast(v8h, *(const uint4*)(wt + col * 32 + kb));
  const v8h A1 = __builtin_bit_cast(v8h, *(const uint4*)(wt + col * 32 + 16 + kb));
  // Bias / fc3 weights pre-swizzled in n-map order: 64B vector loads
  const v16f biasC = *(const v16f*)(ws + WS_BIASF + half * 16);
  const F2x8 w3p = __builtin_bit_cast(F2x8, *(const v16f*)(ws + WS_W3F + half * 16));
  // fc3_b folded into the epilogue accumulator: each half contributes b3/2,
  // the cross-half shuffle-add reassembles the full b3.
  const float b3h = 0.5f * fc3_b[0];

  // Q fragments (g1-invariant, fp16) for both chunks
  HQ qlo[2], qhi[2];
#pragma unroll
  for (int c = 0; c < 2; ++c) {
    const unsigned short* qp = (const unsigned short*)ws + WS_Q16H +
        ((size_t)b * G + g2_0 + (2 * w + c) * 32 + col) * 32;
    qlo[c] = __builtin_bit_cast(HQ, *(const uint4*)(qp + kb));
    qhi[c] = __builtin_bit_cast(HQ, *(const uint4*)(qp + 16 + kb));
  }
  __syncthreads();

  const f2v binit = {b3h, 0.f};
  const f2v z2 = {0.f, 0.f};
  float* op = out + (((size_t)b * G + g1_0) * G) + g2_0 + w * 64 + half * 32 + col;
#pragma unroll 4
  for (int i = 0; i < 8; ++i) {
    const int ra = 2 * i, rb = 2 * i + 1;
    const HQ palo = __builtin_bit_cast(HQ, *(const uint4*)(sPh + ra * 32 + kb));
    const HQ pahi = __builtin_bit_cast(HQ, *(const uint4*)(sPh + ra * 32 + 16 + kb));
    const HQ pblo = __builtin_bit_cast(HQ, *(const uint4*)(sPh + rb * 32 + kb));
    const HQ pbhi = __builtin_bit_cast(HQ, *(const uint4*)(sPh + rb * 32 + 16 + kb));

    // 8 B-frags, 8 MFMAs: 4 independent chains
    const v8h Ba0lo = relu_add(palo, qlo[0]);
    const v8h Ba0hi = relu_add(pahi, qhi[0]);
    const v8h Ba1lo = relu_add(palo, qlo[1]);
    const v8h Ba1hi = relu_add(pahi, qhi[1]);
    const v8h Bb0lo = relu_add(pblo, qlo[0]);
    const v8h Bb0hi = relu_add(pbhi, qhi[0]);
    const v8h Bb1lo = relu_add(pblo, qlo[1]);
    const v8h Bb1hi = relu_add(pbhi, qhi[1]);

    v16f aa0 = __builtin_amdgcn_mfma_f32_32x32x16_f16(A0, Ba0lo, biasC, 0, 0, 0);
    v16f aa1 = __builtin_amdgcn_mfma_f32_32x32x16_f16(A0, Ba1lo, biasC, 0, 0, 0);
    v16f ab0 = __builtin_amdgcn_mfma_f32_32x32x16_f16(A0, Bb0lo, biasC, 0, 0, 0);
    v16f ab1 = __builtin_amdgcn_mfma_f32_32x32x16_f16(A0, Bb1lo, biasC, 0, 0, 0);
    aa0 = __builtin_amdgcn_mfma_f32_32x32x16_f16(A1, Ba0hi, aa0, 0, 0, 0);
    aa1 = __builtin_amdgcn_mfma_f32_32x32x16_f16(A1, Ba1hi, aa1, 0, 0, 0);
    ab0 = __builtin_amdgcn_mfma_f32_32x32x16_f16(A1, Bb0hi, ab0, 0, 0, 0);
    ab1 = __builtin_amdgcn_mfma_f32_32x32x16_f16(A1, Bb1hi, ab1, 0, 0, 0);

    // 4 packed-fp32 epilogues, each with 2 partial accumulators (4-deep
    // dependency chains instead of 8-deep)
    const F2x8 fa0 = __builtin_bit_cast(F2x8, aa0);
    const F2x8 fa1 = __builtin_bit_cast(F2x8, aa1);
    const F2x8 fb0 = __builtin_bit_cast(F2x8, ab0);
    const F2x8 fb1 = __builtin_bit_cast(F2x8, ab1);
    f2v ea0a = binit, ea1a = binit, eb0a = binit, eb1a = binit;
    f2v ea0b = z2, ea1b = z2, eb0b = z2, eb1b = z2;
#pragma unroll
    for (int k = 0; k < 4; ++k) {
      ea0a = __builtin_elementwise_max(fa0.v[k], z2) * w3p.v[k] + ea0a;
      ea1a = __builtin_elementwise_max(fa1.v[k], z2) * w3p.v[k] + ea1a;
      eb0a = __builtin_elementwise_max(fb0.v[k], z2) * w3p.v[k] + eb0a;
      eb1a = __builtin_elementwise_max(fb1.v[k], z2) * w3p.v[k] + eb1a;
      ea0b = __builtin_elementwise_max(fa0.v[k + 4], z2) * w3p.v[k + 4] + ea0b;
      ea1b = __builtin_elementwise_max(fa1.v[k + 4], z2) * w3p.v[k + 4] + ea1b;
      eb0b = __builtin_elementwise_max(fb0.v[k + 4], z2) * w3p.v[k + 4] + eb0b;
      eb1b = __builtin_elementwise_max(fb1.v[k + 4], z2) * w3p.v[k + 4] + eb1b;
    }
    const f2v ea0 = ea0a + ea0b, ea1 = ea1a + ea1b;
    const f2v eb0 = eb0a + eb0b, eb1 = eb1a + eb1b;
    const float sa0 = ea0[0] + ea0[1], sa1 = ea1[0] + ea1[1];
    const float sb0 = eb0[0] + eb0[1], sb1 = eb1[0] + eb1[1];

    // single-shuffle cross-half reduce per row (select-swap)
    float ya = half ? sa1 : sa0;
    float za = half ? sa0 : sa1;
    ya += __shfl_xor(za, 32);
    float yb = half ? sb1 : sb0;
    float zb = half ? sb0 : sb1;
    yb += __shfl_xor(zb, 32);

    op[(size_t)ra * G] = ya;
    op[(size_t)rb * G] = yb;
  }
}

extern "C" void kernel_launch(void* const* d_in, const int* in_sizes, int n_in,
                              void* d_out, int out_size, void* d_ws, size_t ws_size,
                              hipStream_t stream) {
  const float* h     = (const float*)d_in[0];
  const int*   pp    = (const int*)d_in[1];
  const int*   pd    = (const int*)d_in[2];
  const int*   rec   = (const int*)d_in[3];
  const float* Wq1   = (const float*)d_in[4];
  const float* Wk1   = (const float*)d_in[5];
  const float* Wq2   = (const float*)d_in[6];
  const float* Wk2   = (const float*)d_in[7];
  const float* fc1_w = (const float*)d_in[8];
  const float* fc1_b = (const float*)d_in[9];
  const float* fc2_w = (const float*)d_in[10];
  const float* fc2_b = (const float*)d_in[11];
  const float* fc3_w = (const float*)d_in[12];
  const float* fc3_b = (const float*)d_in[13];
  float* out = (float*)d_out;
  float* ws  = (float*)d_ws;

  stage01<<<dim3(256), dim3(256), 0, stream>>>(
      h, pp, pd, rec, Wq1, Wk1, Wq2, Wk2, fc1_w, fc1_b, fc2_w, fc2_b, fc3_w, ws);
  mlp_pairs<<<dim3(2, 32, 32), dim3(256), 0, stream>>>(ws, fc3_b, out);
}

// Round 5
// 140.254 us; speedup vs baseline: 1.6349x; 1.0481x over previous
//
#include <hip/hip_runtime.h>

// Reinsertion: B=32, G=512, D=128, H=4, KD=32. Output (B,G,G) fp32.
//
// R16 = R15 resubmitted verbatim (R15's bench died to an infra "container
// failed twice" error before running; audit found no OOB -- ws poison fill is
// 268MB so the 2.5MB layout is in-bounds). Rationale unchanged:
// Per-rep subtraction says stage01 ~50us (147 = 44.5 fill + 45.7 mlp + rest)
// despite ~10us of work: 256 blocks (1/CU), 5 serial barrier phases, and the
// q/A phases recomputed 8x (once per g-tile). Split:
//  - stage0 (128 blocks = b x head): Q-sets (d-split, 4 waves busy) +
//    A-tables for one head -> ws (256KB). Block 0 does the weight swizzle.
//  - stage1 (512 blocks = b x 32-g tile): loads A from ws (8KB->LDS);
//    phase B with 2 dots/thread from ONE h row (hg/hn split across thread
//    groups); fc1; fp16 pack of P/Q.
//  - mlp_pairs: unchanged from R14 except P/Q ws offsets moved (A region).

#define B 32
#define G 512
#define D 128
#define NH 4
#define KD 32
#define NORMF 0.17677669529663687f  // 1/sqrt(32)

// ws layout:
//  bytes [0, 2048): W2^T f16, wt[col*32 + k]
//  floats [1024, 1056): fc2_b swizzled  bias_sw[half*16 + r] = fc2_b[n(r,half)]
//  floats [1056, 1088): fc3_w swizzled  w3_sw[half*16 + r]   = fc3_w[n(r,half)]
//  floats [4096, 69632): A-tables, A[((b*4 + table)*4 + hh)*128 + d]
//  half-idx [262144, ...): P fp16 [(b*G+g)*32 + j]   (bytes 512KB..1.5MB)
//  half-idx [786432, ...): Q fp16                    (bytes 1.5MB..2.5MB)
#define WS_BIASF 1024
#define WS_W3F   1056
#define WS_AF    4096
#define WS_P16H  262144
#define WS_Q16H  786432

typedef float v16f __attribute__((ext_vector_type(16)));
typedef float f2v __attribute__((ext_vector_type(2)));
typedef _Float16 v8h __attribute__((ext_vector_type(8)));
typedef _Float16 h2v __attribute__((ext_vector_type(2)));

struct HQ { h2v h[4]; };   // 8 halves = 4 VGPRs
struct F2x8 { f2v v[8]; }; // 16 floats as 8 packed pairs

__device__ __forceinline__ v8h relu_add(const HQ& p, const HQ& q) {
  const h2v z = {(_Float16)0.0f, (_Float16)0.0f};
  HQ r;
#pragma unroll
  for (int i = 0; i < 4; ++i)
    r.h[i] = __builtin_elementwise_max(p.h[i] + q.h[i], z);
  return __builtin_bit_cast(v8h, r);
}

// ---------------- Stage 0: Q-sets + A-tables for one (b, head) -------------
// Grid 128 = b*4 + hh; 256 threads.
__global__ __launch_bounds__(256) void stage0(
    const float* __restrict__ h, const int* __restrict__ pp,
    const int* __restrict__ pd,
    const float* __restrict__ Wq1, const float* __restrict__ Wk1,
    const float* __restrict__ Wq2, const float* __restrict__ Wk2,
    const float* __restrict__ fc2_w, const float* __restrict__ fc2_b,
    const float* __restrict__ fc3_w,
    float* __restrict__ ws) {
  const int bx = blockIdx.x;
  const int b = bx >> 2, hh = bx & 3;
  const int t = threadIdx.x;

  // Block 0: emit pre-swizzled stage-2 weight tables (tiny, once).
  if (bx == 0 && t < 32) {
    _Float16* wt = (_Float16*)ws;
#pragma unroll
    for (int k = 0; k < 32; ++k) wt[t * 32 + k] = (_Float16)fc2_w[k * 32 + t];
    const int r = t & 15, hf = t >> 4;
    const int n = (r & 3) + 8 * (r >> 2) + 4 * hf;
    ws[WS_BIASF + t] = fc2_b[n];
    ws[WS_W3F + t]   = fc3_w[n];
  }

  __shared__ float hp[D], hd[D];
  __shared__ float qpart[4][2][KD];
  __shared__ float qq[4 * KD];  // [set*32 + k]

  if (t < 128) {
    hp[t] = h[((size_t)b * G + pp[b]) * D + t];
  } else {
    const int u = t - 128;
    hd[u] = h[((size_t)b * G + pd[b]) * D + u];
  }
  __syncthreads();

  {  // Q-sets: t -> (set s, d-half dh, key k); 64-d partial dots, all 4 waves
    const int s = t >> 6;         // 0:q1p 1:q2p 2:q1d 3:q2d
    const int dh = (t >> 5) & 1;
    const int k = t & 31;
    const float* xs = (s & 2) ? hd : hp;
    const float* wq = ((s & 1) ? Wq2 : Wq1) + hh * D * KD + k;
    float acc = 0.f;
#pragma unroll 8
    for (int i = 0; i < 64; ++i) {
      const int d = dh * 64 + i;
      acc = fmaf(xs[d], wq[d * KD], acc);
    }
    qpart[s][dh][k] = acc;
  }
  __syncthreads();
  if (t < 128) qq[t] = qpart[t >> 5][0][t & 31] + qpart[t >> 5][1][t & 31];
  __syncthreads();

  {  // A-tables: t -> (d, table-pair ps); 32-k dots; write to ws
    const int d = t & 127;
    const int ps = t >> 7;  // 0: Wk1 -> tables 0(pq),2(dp); 1: Wk2 -> 1(po),3(do)
    const float* wk = (ps ? Wk2 : Wk1) + hh * D * KD + d * KD;
    const float* q0 = qq + (ps ? 1 : 0) * KD;
    const float* q1 = qq + (ps ? 3 : 2) * KD;
    float a0 = 0.f, a1 = 0.f;
#pragma unroll
    for (int k = 0; k < KD; ++k) {
      const float wv = wk[k];
      a0 = fmaf(q0[k], wv, a0);
      a1 = fmaf(q1[k], wv, a1);
    }
    float* A = ws + WS_AF + (size_t)b * 2048;
    A[((ps)     * 4 + hh) * 128 + d] = NORMF * a0;
    A[((ps + 2) * 4 + hh) * 128 + d] = NORMF * a1;
  }
}

// ---------------- Stage 1: compat dots + fc1 + fp16 P/Q pack ---------------
// Grid 512 = b*16 + g-tile(32 rows); 256 threads. A-tables from ws.
__global__ __launch_bounds__(256) void stage1(
    const float* __restrict__ h, const int* __restrict__ rec,
    const float* __restrict__ fc1_w, const float* __restrict__ fc1_b,
    float* __restrict__ ws) {
  const int bx = blockIdx.x;
  const int b = bx >> 4, g0 = (bx & 15) * 32;
  const int t = threadIdx.x;

  __shared__ float sA[16][128];   // [table*4 + hh][d]
  __shared__ float sc[32][17];
  __shared__ float sout[32][33];
  __shared__ float sout2[32][33];

  {  // load this batch's A-tables (2048 floats) into LDS
    const float4* src = (const float4*)(ws + WS_AF + (size_t)b * 2048);
    float4* dst = (float4*)&sA[0][0];
    dst[t] = src[t];
    dst[t + 256] = src[t + 256];
  }
  __syncthreads();

  // Phase B: t -> (g, sel); sel = hh + 4*pidx; pidx 0: h[g] vs tables 0,2;
  // pidx 1: h[rec[g]] vs tables 1,3. Each thread: 2 dots over d=128.
  const int gl = t & 31;
  const int sel = t >> 5;
  const int hh = sel & 3, pidx = sel >> 2;
  const int g = g0 + gl;
  const int row = pidx ? rec[b * G + g] : g;
  const float4* x4 = (const float4*)(h + ((size_t)b * G + row) * D);
  const float* A0 = &sA[(pidx ? 1 : 0) * 4 + hh][0];
  const float* A1 = &sA[(pidx ? 3 : 2) * 4 + hh][0];

  float c0 = 0.f, c1 = 0.f;
#pragma unroll 4
  for (int d4 = 0; d4 < 32; ++d4) {
    const float4 x = x4[d4];
    const float4 a = *(const float4*)&A0[4 * d4];
    const float4 bb = *(const float4*)&A1[4 * d4];
    c0 = fmaf(x.x, a.x, fmaf(x.y, a.y, fmaf(x.z, a.z, fmaf(x.w, a.w, c0))));
    c1 = fmaf(x.x, bb.x, fmaf(x.y, bb.y, fmaf(x.z, bb.z, fmaf(x.w, bb.w, c1))));
  }
  sc[gl][(pidx ? 4 : 0) + hh] = c0;   // cpp / cpo
  sc[gl][(pidx ? 12 : 8) + hh] = c1;  // cdp / cdo
  __syncthreads();

  // fc1 decomposition: t -> (g, 4 j's). u layout matches fc1 input order.
  {
    float u[16];
#pragma unroll
    for (int i = 0; i < 16; ++i) u[i] = sc[gl][i];
    const int jb = (t >> 5) * 4;
#pragma unroll
    for (int jj = 0; jj < 4; ++jj) {
      const int j = jb + jj;
      float p = 0.f, q = fc1_b[j];
#pragma unroll
      for (int i = 0; i < 8; ++i) {
        p = fmaf(u[i], fc1_w[i * 32 + j], p);
        q = fmaf(u[8 + i], fc1_w[(8 + i) * 32 + j], q);
      }
      sout[gl][j] = p;
      sout2[gl][j] = q;
    }
  }
  __syncthreads();

  {  // pack to fp16, coalesced uint stores (32 rows x 16 uints each)
    unsigned* dstP = (unsigned*)((unsigned short*)ws + WS_P16H) +
                     ((size_t)b * G + g0) * 16;
    unsigned* dstQ = (unsigned*)((unsigned short*)ws + WS_Q16H) +
                     ((size_t)b * G + g0) * 16;
#pragma unroll
    for (int i = t; i < 512; i += 256) {
      const int row2 = i >> 4, c0i = (2 * i) & 31;
      __fp16 __attribute__((ext_vector_type(2))) pk =
          __builtin_amdgcn_cvt_pkrtz(sout[row2][c0i], sout[row2][c0i + 1]);
      dstP[i] = *(const unsigned*)&pk;
      __fp16 __attribute__((ext_vector_type(2))) qk =
          __builtin_amdgcn_cvt_pkrtz(sout2[row2][c0i], sout2[row2][c0i + 1]);
      dstQ[i] = *(const unsigned*)&qk;
    }
  }
}

// ---------------- Stage 2: per-pair MLP via 32x32x16 f16 MFMA ----------------
// Grid (2,32,32); block 256 = 4 waves; block tile 16 g1 x 256 g2; wave w owns
// chunks {2w,2w+1} of 32 g2. 8 iterations x (2 g1 rows x 2 chunks) = 4
// independent MFMA chains per iteration; epilogue fc3 dot uses 2 partial
// accumulators per chain (8 independent FMA streams). All prologue operands
// come from pre-swizzled ws tables via wide vector loads.
// NOTE: launch bounds (256,2) -- NOT (256,4): the 4-wave hint drops VGPR to 64
// and spills fragments to scratch (R13: +400MB HBM traffic, 3x slower).
__global__ __launch_bounds__(256, 2) void mlp_pairs(
    const float* __restrict__ ws, const float* __restrict__ fc3_b,
    float* __restrict__ out) {
  const int b = blockIdx.z;
  const int g1_0 = blockIdx.y * 16;
  const int g2_0 = blockIdx.x * 256;
  const int t = threadIdx.x;
  const int w = t >> 6, l = t & 63;
  const int col = l & 31;   // pair within chunk
  const int half = l >> 5;  // k-subrange / n-subset selector
  const int kb = half * 8;

  __shared__ __align__(16) unsigned short sPh[16 * 32];  // 1 KB P tile
  {
    const unsigned* Psrc = (const unsigned*)((const unsigned short*)ws + WS_P16H) +
                           ((size_t)b * G + g1_0) * 16;
    ((unsigned*)sPh)[t] = Psrc[t];
  }

  // A-frags from pre-swizzled W2^T f16 [col][k]: 2 x 16B loads
  const unsigned short* wt = (const unsigned short*)ws;
  const v8h A0 = __builtin_bit_cast(v8h, *(const uint4*)(wt + col * 32 + kb));
  const v8h A1 = __builtin_bit_cast(v8h, *(const uint4*)(wt + col * 32 + 16 + kb));
  // Bias / fc3 weights pre-swizzled in n-map order: 64B vector loads
  const v16f biasC = *(const v16f*)(ws + WS_BIASF + half * 16);
  const F2x8 w3p = __builtin_bit_cast(F2x8, *(const v16f*)(ws + WS_W3F + half * 16));
  // fc3_b folded into the epilogue accumulator: each half contributes b3/2,
  // the cross-half shuffle-add reassembles the full b3.
  const float b3h = 0.5f * fc3_b[0];

  // Q fragments (g1-invariant, fp16) for both chunks
  HQ qlo[2], qhi[2];
#pragma unroll
  for (int c = 0; c < 2; ++c) {
    const unsigned short* qp = (const unsigned short*)ws + WS_Q16H +
        ((size_t)b * G + g2_0 + (2 * w + c) * 32 + col) * 32;
    qlo[c] = __builtin_bit_cast(HQ, *(const uint4*)(qp + kb));
    qhi[c] = __builtin_bit_cast(HQ, *(const uint4*)(qp + 16 + kb));
  }
  __syncthreads();

  const f2v binit = {b3h, 0.f};
  const f2v z2 = {0.f, 0.f};
  float* op = out + (((size_t)b * G + g1_0) * G) + g2_0 + w * 64 + half * 32 + col;
#pragma unroll 4
  for (int i = 0; i < 8; ++i) {
    const int ra = 2 * i, rb = 2 * i + 1;
    const HQ palo = __builtin_bit_cast(HQ, *(const uint4*)(sPh + ra * 32 + kb));
    const HQ pahi = __builtin_bit_cast(HQ, *(const uint4*)(sPh + ra * 32 + 16 + kb));
    const HQ pblo = __builtin_bit_cast(HQ, *(const uint4*)(sPh + rb * 32 + kb));
    const HQ pbhi = __builtin_bit_cast(HQ, *(const uint4*)(sPh + rb * 32 + 16 + kb));

    // 8 B-frags, 8 MFMAs: 4 independent chains
    const v8h Ba0lo = relu_add(palo, qlo[0]);
    const v8h Ba0hi = relu_add(pahi, qhi[0]);
    const v8h Ba1lo = relu_add(palo, qlo[1]);
    const v8h Ba1hi = relu_add(pahi, qhi[1]);
    const v8h Bb0lo = relu_add(pblo, qlo[0]);
    const v8h Bb0hi = relu_add(pbhi, qhi[0]);
    const v8h Bb1lo = relu_add(pblo, qlo[1]);
    const v8h Bb1hi = relu_add(pbhi, qhi[1]);

    v16f aa0 = __builtin_amdgcn_mfma_f32_32x32x16_f16(A0, Ba0lo, biasC, 0, 0, 0);
    v16f aa1 = __builtin_amdgcn_mfma_f32_32x32x16_f16(A0, Ba1lo, biasC, 0, 0, 0);
    v16f ab0 = __builtin_amdgcn_mfma_f32_32x32x16_f16(A0, Bb0lo, biasC, 0, 0, 0);
    v16f ab1 = __builtin_amdgcn_mfma_f32_32x32x16_f16(A0, Bb1lo, biasC, 0, 0, 0);
    aa0 = __builtin_amdgcn_mfma_f32_32x32x16_f16(A1, Ba0hi, aa0, 0, 0, 0);
    aa1 = __builtin_amdgcn_mfma_f32_32x32x16_f16(A1, Ba1hi, aa1, 0, 0, 0);
    ab0 = __builtin_amdgcn_mfma_f32_32x32x16_f16(A1, Bb0hi, ab0, 0, 0, 0);
    ab1 = __builtin_amdgcn_mfma_f32_32x32x16_f16(A1, Bb1hi, ab1, 0, 0, 0);

    // 4 packed-fp32 epilogues, each with 2 partial accumulators (4-deep
    // dependency chains instead of 8-deep)
    const F2x8 fa0 = __builtin_bit_cast(F2x8, aa0);
    const F2x8 fa1 = __builtin_bit_cast(F2x8, aa1);
    const F2x8 fb0 = __builtin_bit_cast(F2x8, ab0);
    const F2x8 fb1 = __builtin_bit_cast(F2x8, ab1);
    f2v ea0a = binit, ea1a = binit, eb0a = binit, eb1a = binit;
    f2v ea0b = z2, ea1b = z2, eb0b = z2, eb1b = z2;
#pragma unroll
    for (int k = 0; k < 4; ++k) {
      ea0a = __builtin_elementwise_max(fa0.v[k], z2) * w3p.v[k] + ea0a;
      ea1a = __builtin_elementwise_max(fa1.v[k], z2) * w3p.v[k] + ea1a;
      eb0a = __builtin_elementwise_max(fb0.v[k], z2) * w3p.v[k] + eb0a;
      eb1a = __builtin_elementwise_max(fb1.v[k], z2) * w3p.v[k] + eb1a;
      ea0b = __builtin_elementwise_max(fa0.v[k + 4], z2) * w3p.v[k + 4] + ea0b;
      ea1b = __builtin_elementwise_max(fa1.v[k + 4], z2) * w3p.v[k + 4] + ea1b;
      eb0b = __builtin_elementwise_max(fb0.v[k + 4], z2) * w3p.v[k + 4] + eb0b;
      eb1b = __builtin_elementwise_max(fb1.v[k + 4], z2) * w3p.v[k + 4] + eb1b;
    }
    const f2v ea0 = ea0a + ea0b, ea1 = ea1a + ea1b;
    const f2v eb0 = eb0a + eb0b, eb1 = eb1a + eb1b;
    const float sa0 = ea0[0] + ea0[1], sa1 = ea1[0] + ea1[1];
    const float sb0 = eb0[0] + eb0[1], sb1 = eb1[0] + eb1[1];

    // single-shuffle cross-half reduce per row (select-swap)
    float ya = half ? sa1 : sa0;
    float za = half ? sa0 : sa1;
    ya += __shfl_xor(za, 32);
    float yb = half ? sb1 : sb0;
    float zb = half ? sb0 : sb1;
    yb += __shfl_xor(zb, 32);

    op[(size_t)ra * G] = ya;
    op[(size_t)rb * G] = yb;
  }
}

extern "C" void kernel_launch(void* const* d_in, const int* in_sizes, int n_in,
                              void* d_out, int out_size, void* d_ws, size_t ws_size,
                              hipStream_t stream) {
  const float* h     = (const float*)d_in[0];
  const int*   pp    = (const int*)d_in[1];
  const int*   pd    = (const int*)d_in[2];
  const int*   rec   = (const int*)d_in[3];
  const float* Wq1   = (const float*)d_in[4];
  const float* Wk1   = (const float*)d_in[5];
  const float* Wq2   = (const float*)d_in[6];
  const float* Wk2   = (const float*)d_in[7];
  const float* fc1_w = (const float*)d_in[8];
  const float* fc1_b = (const float*)d_in[9];
  const float* fc2_w = (const float*)d_in[10];
  const float* fc2_b = (const float*)d_in[11];
  const float* fc3_w = (const float*)d_in[12];
  const float* fc3_b = (const float*)d_in[13];
  float* out = (float*)d_out;
  float* ws  = (float*)d_ws;

  stage0<<<dim3(128), dim3(256), 0, stream>>>(
      h, pp, pd, Wq1, Wk1, Wq2, Wk2, fc2_w, fc2_b, fc3_w, ws);
  stage1<<<dim3(512), dim3(256), 0, stream>>>(h, rec, fc1_w, fc1_b, ws);
  mlp_pairs<<<dim3(2, 32, 32), dim3(256), 0, stream>>>(ws, fc3_b, out);
}

// Round 6
// 137.218 us; speedup vs baseline: 1.6711x; 1.0221x over previous
//
#include <hip/hip_runtime.h>

// Reinsertion: B=32, G=512, D=128, H=4, KD=32. Output (B,G,G) fp32.
//
// R17 = R16 + mlp_pairs ILP fix. Evidence: VGPR_Count=76 proves the compiler
// serialized the 4 MFMA chains (4x16 f32 accumulators alone need 64 VGPRs) to
// minimize registers, exposing MFMA latency with only ~2 waves/SIMD resident.
// Counter triangulation (VALUBusy 58%, MfmaUtil 15%, work ~22k cy/SIMD) also
// implies engine clock ~0.9GHz on these short dispatches -- so issue
// efficiency is the only controllable lever. Fix: sched_barrier(0) between
// the 8-MFMA cluster and the epilogue cluster forces all accumulators live
// (-> ~150 VGPR, still under the (256,2) cap of 256, no spill) and restores
// 4-chain ILP; next-iter ds_reads can hoist above the epilogue.

#define B 32
#define G 512
#define D 128
#define NH 4
#define KD 32
#define NORMF 0.17677669529663687f  // 1/sqrt(32)

// ws layout:
//  bytes [0, 2048): W2^T f16, wt[col*32 + k]
//  floats [1024, 1056): fc2_b swizzled  bias_sw[half*16 + r] = fc2_b[n(r,half)]
//  floats [1056, 1088): fc3_w swizzled  w3_sw[half*16 + r]   = fc3_w[n(r,half)]
//  floats [4096, 69632): A-tables, A[((b*4 + table)*4 + hh)*128 + d]
//  half-idx [262144, ...): P fp16 [(b*G+g)*32 + j]   (bytes 512KB..1.5MB)
//  half-idx [786432, ...): Q fp16                    (bytes 1.5MB..2.5MB)
#define WS_BIASF 1024
#define WS_W3F   1056
#define WS_AF    4096
#define WS_P16H  262144
#define WS_Q16H  786432

typedef float v16f __attribute__((ext_vector_type(16)));
typedef float f2v __attribute__((ext_vector_type(2)));
typedef _Float16 v8h __attribute__((ext_vector_type(8)));
typedef _Float16 h2v __attribute__((ext_vector_type(2)));

struct HQ { h2v h[4]; };   // 8 halves = 4 VGPRs
struct F2x8 { f2v v[8]; }; // 16 floats as 8 packed pairs

__device__ __forceinline__ v8h relu_add(const HQ& p, const HQ& q) {
  const h2v z = {(_Float16)0.0f, (_Float16)0.0f};
  HQ r;
#pragma unroll
  for (int i = 0; i < 4; ++i)
    r.h[i] = __builtin_elementwise_max(p.h[i] + q.h[i], z);
  return __builtin_bit_cast(v8h, r);
}

// ---------------- Stage 0: Q-sets + A-tables for one (b, head) -------------
// Grid 128 = b*4 + hh; 256 threads.
__global__ __launch_bounds__(256) void stage0(
    const float* __restrict__ h, const int* __restrict__ pp,
    const int* __restrict__ pd,
    const float* __restrict__ Wq1, const float* __restrict__ Wk1,
    const float* __restrict__ Wq2, const float* __restrict__ Wk2,
    const float* __restrict__ fc2_w, const float* __restrict__ fc2_b,
    const float* __restrict__ fc3_w,
    float* __restrict__ ws) {
  const int bx = blockIdx.x;
  const int b = bx >> 2, hh = bx & 3;
  const int t = threadIdx.x;

  // Block 0: emit pre-swizzled stage-2 weight tables (tiny, once).
  if (bx == 0 && t < 32) {
    _Float16* wt = (_Float16*)ws;
#pragma unroll
    for (int k = 0; k < 32; ++k) wt[t * 32 + k] = (_Float16)fc2_w[k * 32 + t];
    const int r = t & 15, hf = t >> 4;
    const int n = (r & 3) + 8 * (r >> 2) + 4 * hf;
    ws[WS_BIASF + t] = fc2_b[n];
    ws[WS_W3F + t]   = fc3_w[n];
  }

  __shared__ float hp[D], hd[D];
  __shared__ float qpart[4][2][KD];
  __shared__ float qq[4 * KD];  // [set*32 + k]

  if (t < 128) {
    hp[t] = h[((size_t)b * G + pp[b]) * D + t];
  } else {
    const int u = t - 128;
    hd[u] = h[((size_t)b * G + pd[b]) * D + u];
  }
  __syncthreads();

  {  // Q-sets: t -> (set s, d-half dh, key k); 64-d partial dots, all 4 waves
    const int s = t >> 6;         // 0:q1p 1:q2p 2:q1d 3:q2d
    const int dh = (t >> 5) & 1;
    const int k = t & 31;
    const float* xs = (s & 2) ? hd : hp;
    const float* wq = ((s & 1) ? Wq2 : Wq1) + hh * D * KD + k;
    float acc = 0.f;
#pragma unroll 8
    for (int i = 0; i < 64; ++i) {
      const int d = dh * 64 + i;
      acc = fmaf(xs[d], wq[d * KD], acc);
    }
    qpart[s][dh][k] = acc;
  }
  __syncthreads();
  if (t < 128) qq[t] = qpart[t >> 5][0][t & 31] + qpart[t >> 5][1][t & 31];
  __syncthreads();

  {  // A-tables: t -> (d, table-pair ps); 32-k dots; write to ws
    const int d = t & 127;
    const int ps = t >> 7;  // 0: Wk1 -> tables 0(pq),2(dp); 1: Wk2 -> 1(po),3(do)
    const float* wk = (ps ? Wk2 : Wk1) + hh * D * KD + d * KD;
    const float* q0 = qq + (ps ? 1 : 0) * KD;
    const float* q1 = qq + (ps ? 3 : 2) * KD;
    float a0 = 0.f, a1 = 0.f;
#pragma unroll
    for (int k = 0; k < KD; ++k) {
      const float wv = wk[k];
      a0 = fmaf(q0[k], wv, a0);
      a1 = fmaf(q1[k], wv, a1);
    }
    float* A = ws + WS_AF + (size_t)b * 2048;
    A[((ps)     * 4 + hh) * 128 + d] = NORMF * a0;
    A[((ps + 2) * 4 + hh) * 128 + d] = NORMF * a1;
  }
}

// ---------------- Stage 1: compat dots + fc1 + fp16 P/Q pack ---------------
// Grid 512 = b*16 + g-tile(32 rows); 256 threads. A-tables from ws.
__global__ __launch_bounds__(256) void stage1(
    const float* __restrict__ h, const int* __restrict__ rec,
    const float* __restrict__ fc1_w, const float* __restrict__ fc1_b,
    float* __restrict__ ws) {
  const int bx = blockIdx.x;
  const int b = bx >> 4, g0 = (bx & 15) * 32;
  const int t = threadIdx.x;

  __shared__ float sA[16][128];   // [table*4 + hh][d]
  __shared__ float sc[32][17];
  __shared__ float sout[32][33];
  __shared__ float sout2[32][33];

  {  // load this batch's A-tables (2048 floats) into LDS
    const float4* src = (const float4*)(ws + WS_AF + (size_t)b * 2048);
    float4* dst = (float4*)&sA[0][0];
    dst[t] = src[t];
    dst[t + 256] = src[t + 256];
  }
  __syncthreads();

  // Phase B: t -> (g, sel); sel = hh + 4*pidx; pidx 0: h[g] vs tables 0,2;
  // pidx 1: h[rec[g]] vs tables 1,3. Each thread: 2 dots over d=128.
  const int gl = t & 31;
  const int sel = t >> 5;
  const int hh = sel & 3, pidx = sel >> 2;
  const int g = g0 + gl;
  const int row = pidx ? rec[b * G + g] : g;
  const float4* x4 = (const float4*)(h + ((size_t)b * G + row) * D);
  const float* A0 = &sA[(pidx ? 1 : 0) * 4 + hh][0];
  const float* A1 = &sA[(pidx ? 3 : 2) * 4 + hh][0];

  float c0 = 0.f, c1 = 0.f;
#pragma unroll 4
  for (int d4 = 0; d4 < 32; ++d4) {
    const float4 x = x4[d4];
    const float4 a = *(const float4*)&A0[4 * d4];
    const float4 bb = *(const float4*)&A1[4 * d4];
    c0 = fmaf(x.x, a.x, fmaf(x.y, a.y, fmaf(x.z, a.z, fmaf(x.w, a.w, c0))));
    c1 = fmaf(x.x, bb.x, fmaf(x.y, bb.y, fmaf(x.z, bb.z, fmaf(x.w, bb.w, c1))));
  }
  sc[gl][(pidx ? 4 : 0) + hh] = c0;   // cpp / cpo
  sc[gl][(pidx ? 12 : 8) + hh] = c1;  // cdp / cdo
  __syncthreads();

  // fc1 decomposition: t -> (g, 4 j's). u layout matches fc1 input order.
  {
    float u[16];
#pragma unroll
    for (int i = 0; i < 16; ++i) u[i] = sc[gl][i];
    const int jb = (t >> 5) * 4;
#pragma unroll
    for (int jj = 0; jj < 4; ++jj) {
      const int j = jb + jj;
      float p = 0.f, q = fc1_b[j];
#pragma unroll
      for (int i = 0; i < 8; ++i) {
        p = fmaf(u[i], fc1_w[i * 32 + j], p);
        q = fmaf(u[8 + i], fc1_w[(8 + i) * 32 + j], q);
      }
      sout[gl][j] = p;
      sout2[gl][j] = q;
    }
  }
  __syncthreads();

  {  // pack to fp16, coalesced uint stores (32 rows x 16 uints each)
    unsigned* dstP = (unsigned*)((unsigned short*)ws + WS_P16H) +
                     ((size_t)b * G + g0) * 16;
    unsigned* dstQ = (unsigned*)((unsigned short*)ws + WS_Q16H) +
                     ((size_t)b * G + g0) * 16;
#pragma unroll
    for (int i = t; i < 512; i += 256) {
      const int row2 = i >> 4, c0i = (2 * i) & 31;
      __fp16 __attribute__((ext_vector_type(2))) pk =
          __builtin_amdgcn_cvt_pkrtz(sout[row2][c0i], sout[row2][c0i + 1]);
      dstP[i] = *(const unsigned*)&pk;
      __fp16 __attribute__((ext_vector_type(2))) qk =
          __builtin_amdgcn_cvt_pkrtz(sout2[row2][c0i], sout2[row2][c0i + 1]);
      dstQ[i] = *(const unsigned*)&qk;
    }
  }
}

// ---------------- Stage 2: per-pair MLP via 32x32x16 f16 MFMA ----------------
// Grid (2,32,32); block 256 = 4 waves; block tile 16 g1 x 256 g2; wave w owns
// chunks {2w,2w+1} of 32 g2. 8 iterations x (2 g1 rows x 2 chunks) = 4
// independent MFMA chains per iteration; sched_barrier(0) after the MFMA
// cluster keeps all 4 accumulator sets live (defeats the register-minimizing
// serialization seen at VGPR=76) so the chains' epilogues overlap MFMA
// latency. Epilogue fc3 dot uses 2 partial accumulators per chain.
// NOTE: launch bounds (256,2) -- NOT (256,4): the 4-wave hint drops VGPR to 64
// and spills fragments to scratch (R13: +400MB HBM traffic, 3x slower).
__global__ __launch_bounds__(256, 2) void mlp_pairs(
    const float* __restrict__ ws, const float* __restrict__ fc3_b,
    float* __restrict__ out) {
  const int b = blockIdx.z;
  const int g1_0 = blockIdx.y * 16;
  const int g2_0 = blockIdx.x * 256;
  const int t = threadIdx.x;
  const int w = t >> 6, l = t & 63;
  const int col = l & 31;   // pair within chunk
  const int half = l >> 5;  // k-subrange / n-subset selector
  const int kb = half * 8;

  __shared__ __align__(16) unsigned short sPh[16 * 32];  // 1 KB P tile
  {
    const unsigned* Psrc = (const unsigned*)((const unsigned short*)ws + WS_P16H) +
                           ((size_t)b * G + g1_0) * 16;
    ((unsigned*)sPh)[t] = Psrc[t];
  }

  // A-frags from pre-swizzled W2^T f16 [col][k]: 2 x 16B loads
  const unsigned short* wt = (const unsigned short*)ws;
  const v8h A0 = __builtin_bit_cast(v8h, *(const uint4*)(wt + col * 32 + kb));
  const v8h A1 = __builtin_bit_cast(v8h, *(const uint4*)(wt + col * 32 + 16 + kb));
  // Bias / fc3 weights pre-swizzled in n-map order: 64B vector loads
  const v16f biasC = *(const v16f*)(ws + WS_BIASF + half * 16);
  const F2x8 w3p = __builtin_bit_cast(F2x8, *(const v16f*)(ws + WS_W3F + half * 16));
  // fc3_b folded into the epilogue accumulator: each half contributes b3/2,
  // the cross-half shuffle-add reassembles the full b3.
  const float b3h = 0.5f * fc3_b[0];

  // Q fragments (g1-invariant, fp16) for both chunks
  HQ qlo[2], qhi[2];
#pragma unroll
  for (int c = 0; c < 2; ++c) {
    const unsigned short* qp = (const unsigned short*)ws + WS_Q16H +
        ((size_t)b * G + g2_0 + (2 * w + c) * 32 + col) * 32;
    qlo[c] = __builtin_bit_cast(HQ, *(const uint4*)(qp + kb));
    qhi[c] = __builtin_bit_cast(HQ, *(const uint4*)(qp + 16 + kb));
  }
  __syncthreads();

  const f2v binit = {b3h, 0.f};
  const f2v z2 = {0.f, 0.f};
  float* op = out + (((size_t)b * G + g1_0) * G) + g2_0 + w * 64 + half * 32 + col;
#pragma unroll 4
  for (int i = 0; i < 8; ++i) {
    const int ra = 2 * i, rb = 2 * i + 1;
    const HQ palo = __builtin_bit_cast(HQ, *(const uint4*)(sPh + ra * 32 + kb));
    const HQ pahi = __builtin_bit_cast(HQ, *(const uint4*)(sPh + ra * 32 + 16 + kb));
    const HQ pblo = __builtin_bit_cast(HQ, *(const uint4*)(sPh + rb * 32 + kb));
    const HQ pbhi = __builtin_bit_cast(HQ, *(const uint4*)(sPh + rb * 32 + 16 + kb));

    // 8 B-frags, 8 MFMAs: 4 independent chains
    const v8h Ba0lo = relu_add(palo, qlo[0]);
    const v8h Ba0hi = relu_add(pahi, qhi[0]);
    const v8h Ba1lo = relu_add(palo, qlo[1]);
    const v8h Ba1hi = relu_add(pahi, qhi[1]);
    const v8h Bb0lo = relu_add(pblo, qlo[0]);
    const v8h Bb0hi = relu_add(pbhi, qhi[0]);
    const v8h Bb1lo = relu_add(pblo, qlo[1]);
    const v8h Bb1hi = relu_add(pbhi, qhi[1]);

    v16f aa0 = __builtin_amdgcn_mfma_f32_32x32x16_f16(A0, Ba0lo, biasC, 0, 0, 0);
    v16f aa1 = __builtin_amdgcn_mfma_f32_32x32x16_f16(A0, Ba1lo, biasC, 0, 0, 0);
    v16f ab0 = __builtin_amdgcn_mfma_f32_32x32x16_f16(A0, Bb0lo, biasC, 0, 0, 0);
    v16f ab1 = __builtin_amdgcn_mfma_f32_32x32x16_f16(A0, Bb1lo, biasC, 0, 0, 0);
    aa0 = __builtin_amdgcn_mfma_f32_32x32x16_f16(A1, Ba0hi, aa0, 0, 0, 0);
    aa1 = __builtin_amdgcn_mfma_f32_32x32x16_f16(A1, Ba1hi, aa1, 0, 0, 0);
    ab0 = __builtin_amdgcn_mfma_f32_32x32x16_f16(A1, Bb0hi, ab0, 0, 0, 0);
    ab1 = __builtin_amdgcn_mfma_f32_32x32x16_f16(A1, Bb1hi, ab1, 0, 0, 0);

    // Fence: no epilogue instruction may be hoisted above this point, no MFMA
    // may sink below it -> all 4 accumulator sets live simultaneously.
    __builtin_amdgcn_sched_barrier(0);

    // 4 packed-fp32 epilogues, each with 2 partial accumulators (4-deep
    // dependency chains instead of 8-deep)
    const F2x8 fa0 = __builtin_bit_cast(F2x8, aa0);
    const F2x8 fa1 = __builtin_bit_cast(F2x8, aa1);
    const F2x8 fb0 = __builtin_bit_cast(F2x8, ab0);
    const F2x8 fb1 = __builtin_bit_cast(F2x8, ab1);
    f2v ea0a = binit, ea1a = binit, eb0a = binit, eb1a = binit;
    f2v ea0b = z2, ea1b = z2, eb0b = z2, eb1b = z2;
#pragma unroll
    for (int k = 0; k < 4; ++k) {
      ea0a = __builtin_elementwise_max(fa0.v[k], z2) * w3p.v[k] + ea0a;
      ea1a = __builtin_elementwise_max(fa1.v[k], z2) * w3p.v[k] + ea1a;
      eb0a = __builtin_elementwise_max(fb0.v[k], z2) * w3p.v[k] + eb0a;
      eb1a = __builtin_elementwise_max(fb1.v[k], z2) * w3p.v[k] + eb1a;
      ea0b = __builtin_elementwise_max(fa0.v[k + 4], z2) * w3p.v[k + 4] + ea0b;
      ea1b = __builtin_elementwise_max(fa1.v[k + 4], z2) * w3p.v[k + 4] + ea1b;
      eb0b = __builtin_elementwise_max(fb0.v[k + 4], z2) * w3p.v[k + 4] + eb0b;
      eb1b = __builtin_elementwise_max(fb1.v[k + 4], z2) * w3p.v[k + 4] + eb1b;
    }
    const f2v ea0 = ea0a + ea0b, ea1 = ea1a + ea1b;
    const f2v eb0 = eb0a + eb0b, eb1 = eb1a + eb1b;
    const float sa0 = ea0[0] + ea0[1], sa1 = ea1[0] + ea1[1];
    const float sb0 = eb0[0] + eb0[1], sb1 = eb1[0] + eb1[1];

    // single-shuffle cross-half reduce per row (select-swap)
    float ya = half ? sa1 : sa0;
    float za = half ? sa0 : sa1;
    ya += __shfl_xor(za, 32);
    float yb = half ? sb1 : sb0;
    float zb = half ? sb0 : sb1;
    yb += __shfl_xor(zb, 32);

    op[(size_t)ra * G] = ya;
    op[(size_t)rb * G] = yb;
  }
}

extern "C" void kernel_launch(void* const* d_in, const int* in_sizes, int n_in,
                              void* d_out, int out_size, void* d_ws, size_t ws_size,
                              hipStream_t stream) {
  const float* h     = (const float*)d_in[0];
  const int*   pp    = (const int*)d_in[1];
  const int*   pd    = (const int*)d_in[2];
  const int*   rec   = (const int*)d_in[3];
  const float* Wq1   = (const float*)d_in[4];
  const float* Wk1   = (const float*)d_in[5];
  const float* Wq2   = (const float*)d_in[6];
  const float* Wk2   = (const float*)d_in[7];
  const float* fc1_w = (const float*)d_in[8];
  const float* fc1_b = (const float*)d_in[9];
  const float* fc2_w = (const float*)d_in[10];
  const float* fc2_b = (const float*)d_in[11];
  const float* fc3_w = (const float*)d_in[12];
  const float* fc3_b = (const float*)d_in[13];
  float* out = (float*)d_out;
  float* ws  = (float*)d_ws;

  stage0<<<dim3(128), dim3(256), 0, stream>>>(
      h, pp, pd, Wq1, Wk1, Wq2, Wk2, fc2_w, fc2_b, fc3_w, ws);
  stage1<<<dim3(512), dim3(256), 0, stream>>>(h, rec, fc1_w, fc1_b, ws);
  mlp_pairs<<<dim3(2, 32, 32), dim3(256), 0, stream>>>(ws, fc3_b, out);
}